// Round 4
// baseline (158.572 us; speedup 1.0000x reference)
//
#include <hip/hip_runtime.h>

#define NPARC 289
#define NOUT  578
#define DIMK  512
#define BATCH 32768

typedef __bf16 bf16x8 __attribute__((ext_vector_type(8)));
typedef float floatx16 __attribute__((ext_vector_type(16)));

__device__ __forceinline__ unsigned short f2bf(float f) {
    unsigned u = __float_as_uint(f);
    u = (u + 0x7fffu + ((u >> 16) & 1u)) >> 16;
    return (unsigned short)u;
}

// ROUND 9/10: 32x32x16 fragments. Wp layout: [t][ks][lane][8] bf16,
// t in [0,20) = 32-col tile, ks in [0,32) = K-16 step.
// lane: m = t*32 + (lane&31), k = ks*16 + (lane>>5)*8 + j.  Cols >= 578 zero.
__global__ void prep_w(const float* __restrict__ W, unsigned short* __restrict__ Wp) {
    int wid = threadIdx.x >> 6;
    int lane = threadIdx.x & 63;
    int col = blockIdx.x * 4 + wid;          // [0, 640)
    int k = lane * 8;                        // [0, 512)
    unsigned short v[8];
    if (col < NOUT) {
        const float* src = W + (size_t)col * DIMK + k;
        #pragma unroll
        for (int j = 0; j < 8; ++j) v[j] = f2bf(src[j]);
    } else {
        #pragma unroll
        for (int j = 0; j < 8; ++j) v[j] = 0;
    }
    int t    = col >> 5;
    int ks   = lane >> 1;        // k>>4
    int half = lane & 1;         // (k>>3)&1
    int ln   = half * 32 + (col & 31);
    uint4 o;
    o.x = (unsigned)v[0] | ((unsigned)v[1] << 16);
    o.y = (unsigned)v[2] | ((unsigned)v[3] << 16);
    o.z = (unsigned)v[4] | ((unsigned)v[5] << 16);
    o.w = (unsigned)v[6] | ((unsigned)v[7] << 16);
    *(uint4*)(Wp + (size_t)((t * 32 + ks) * 64 + ln) * 8) = o;
}

// ROUND 10 (= Round 9 re-run; bench infra failed, no counters — theory
// unrefuted, resubmitting identical kernel for a clean A/B).
// No-LDS dataflow kernel: R0-R2 were stuck at ~43 us with every pipe <=30%
// busy — the serial stage->barrier->compute structure was the bottleneck,
// not any pipe. Each lane loads its own B-fragment (8 consecutive fp32 of
// one input row = 2 x dwordx4) straight from global, converts in-reg,
// MFMAs. No staging pass, no barriers in the main loop, no bank conflicts.
// Sharing: 8 waves = (st in {0,1} 32-sample tiles) x (g in {0..3} 160-col
// groups); the 4 same-st waves read identical B addresses ~in lockstep ->
// L1/L2 absorbs the 4x reuse; W slices read once per block (335 MB L2).
// 32x32x16 MFMA: 19% more FLOP/cyc than 16x16x32, half the loads (1:1
// aw:MFMA). acc = 5 x floatx16 = 80 regs; target <=128 total for 4 w/SIMD.
__global__ __launch_bounds__(512, 4) void fused_kernel(
    const float* __restrict__ inputs, const float* __restrict__ targets,
    const float* __restrict__ bias, const unsigned short* __restrict__ Wp,
    float* __restrict__ out)
{
    __shared__ float R[8][32][3];            // 3 KiB reduce buffer
    const int tid  = threadIdx.x;
    const int wid  = tid >> 6;               // 0..7
    const int lane = tid & 63;
    const int st   = wid & 1;                // sample 32-tile
    const int g    = wid >> 1;               // col group (160 cols = 5 tiles)
    const int base = blockIdx.x * 64;
    const int sample = base + st * 32 + (lane & 31);

    const float* brow = inputs + (size_t)sample * DIMK + ((lane >> 5) << 3);
    const bf16x8* awp = (const bf16x8*)Wp + (size_t)(g * 5 * 32) * 64 + lane;

    floatx16 acc[5];
    #pragma unroll
    for (int t5 = 0; t5 < 5; ++t5) acc[t5] = (floatx16)0.f;

    // ---- main loop: pure dataflow, depth-1 B prefetch, no barriers ----
    float4 bA = *(const float4*)(brow);
    float4 bB = *(const float4*)(brow + 4);
    #pragma unroll 2
    for (int ks = 0; ks < 32; ++ks) {
        float4 cA = bA, cB = bB;
        int nk = (ks + 1) & 31;              // wraps to 0 (discarded), stays in-bounds
        bA = *(const float4*)(brow + nk * 16);
        bB = *(const float4*)(brow + nk * 16 + 4);
        union { __bf16 h[8]; bf16x8 v; } bb;
        bb.h[0] = (__bf16)cA.x; bb.h[1] = (__bf16)cA.y;
        bb.h[2] = (__bf16)cA.z; bb.h[3] = (__bf16)cA.w;
        bb.h[4] = (__bf16)cB.x; bb.h[5] = (__bf16)cB.y;
        bb.h[6] = (__bf16)cB.z; bb.h[7] = (__bf16)cB.w;
        #pragma unroll
        for (int t5 = 0; t5 < 5; ++t5) {
            bf16x8 aw = awp[(size_t)(t5 * 32 + ks) * 64];
            acc[t5] = __builtin_amdgcn_mfma_f32_32x32x16_bf16(aw, bb.v, acc[t5], 0, 0, 0);
        }
    }

    // ---- epilogue: fold 5 col-tiles into per-sample partials ----
    float2 t2 = *(const float2*)(targets + 2 * sample);
    float xs = 0.5f * t2.x;                  // revolutions: sin(pi*z) = v_sin(z/2)
    float ys = 0.5f * t2.y;

    float pd = 0.f, pr = 0.f, pim = 0.f;

    #pragma unroll
    for (int t5 = 0; t5 < 5; ++t5)
        #pragma unroll
        for (int reg = 0; reg < 16; ++reg) {
            int colw = (g * 5 + t5) * 32 + (reg & 3) + 8 * (reg >> 2) + 4 * (lane >> 5);
            if (colw < NOUT) {
                bool im = (colw >= NPARC);
                int idx = im ? colw - NPARC : colw;
                int r = idx / 17;
                int c = idx - r * 17;
                float cf = (float)c, rf = (float)r;
                float val = acc[t5][reg] + bias[colw];
                float u = fmaf(cf, xs, rf * ys);
                u = __builtin_amdgcn_fractf(u);
                float sn = __builtin_amdgcn_sinf(u);
                float cs = __builtin_amdgcn_cosf(u);
                float a1 = im ? -sn : cs;
                float a2 = im ?  cs : sn;
                pd  = fmaf(val, val, pd);
                pr  = fmaf(val, a1, pr);
                pim = fmaf(val, a2, pim);
            }
        }

    // lane L and L^32 hold disjoint col-rows of the same sample: fold halves
    pd  += __shfl_xor(pd, 32, 64);
    pr  += __shfl_xor(pr, 32, 64);
    pim += __shfl_xor(pim, 32, 64);

    if (lane < 32) {
        R[wid][lane][0] = pd;
        R[wid][lane][1] = pr;
        R[wid][lane][2] = pim;
    }
    __syncthreads();

    if (tid < 64) {
        int s5 = tid >> 5, j = tid & 31;
        float sd = 0.f, sr = 0.f, si = 0.f;
        #pragma unroll
        for (int gg = 0; gg < 4; ++gg) {
            sd += R[gg * 2 + s5][j][0];
            sr += R[gg * 2 + s5][j][1];
            si += R[gg * 2 + s5][j][2];
        }
        out[base + tid] = (sr * sr + si * si) / (4.0f * sd);
    }
}

extern "C" void kernel_launch(void* const* d_in, const int* in_sizes, int n_in,
                              void* d_out, int out_size, void* d_ws, size_t ws_size,
                              hipStream_t stream) {
    const float* inputs  = (const float*)d_in[0];
    const float* targets = (const float*)d_in[1];
    const float* W       = (const float*)d_in[2];
    const float* bias    = (const float*)d_in[3];
    unsigned short* Wp   = (unsigned short*)d_ws;   // 640 KiB of ws

    prep_w<<<160, 256, 0, stream>>>(W, Wp);
    fused_kernel<<<BATCH / 64, 512, 0, stream>>>(inputs, targets, bias, Wp, (float*)d_out);
}

// Round 5
// 121.227 us; speedup vs baseline: 1.3081x; 1.3081x over previous
//
#include <hip/hip_runtime.h>

#define NPARC 289
#define NOUT  578
#define DIMK  512
#define BATCH 32768

typedef __bf16 bf16x8 __attribute__((ext_vector_type(8)));
typedef float floatx4 __attribute__((ext_vector_type(4)));

__device__ __forceinline__ unsigned short f2bf(float f) {
    unsigned u = __float_as_uint(f);
    u = (u + 0x7fffu + ((u >> 16) & 1u)) >> 16;
    return (unsigned short)u;
}

// ROUND 11 prep: INTERLEAVED col slots — slot 2j = re col j, slot 2j+1 =
// im col j (orig row j+289) so the fused epilogue shares one sincos per
// (re,im) pair. Fragment order unchanged (16x16x32 A-operand):
// m = ct*16 + (lane&15), k = ks*32 + (lane>>4)*8 + j. Slots >= 578 zero.
__global__ void prep_w(const float* __restrict__ W, unsigned short* __restrict__ Wp) {
    int wid = threadIdx.x >> 6;
    int lane = threadIdx.x & 63;
    int slot = blockIdx.x * 4 + wid;         // [0, 640)
    int k = lane * 8;
    unsigned short v[8];
    if (slot < NOUT) {
        int o = (slot & 1) ? NPARC + (slot >> 1) : (slot >> 1);
        const float* src = W + (size_t)o * DIMK + k;
        #pragma unroll
        for (int j = 0; j < 8; ++j) v[j] = f2bf(src[j]);
    } else {
        #pragma unroll
        for (int j = 0; j < 8; ++j) v[j] = 0;
    }
    int ct = slot >> 4;
    int ks = k >> 5;
    int ln = (((k >> 3) & 3) << 4) + (slot & 15);
    uint4 o4;
    o4.x = (unsigned)v[0] | ((unsigned)v[1] << 16);
    o4.y = (unsigned)v[2] | ((unsigned)v[3] << 16);
    o4.z = (unsigned)v[4] | ((unsigned)v[5] << 16);
    o4.w = (unsigned)v[6] | ((unsigned)v[7] << 16);
    *(uint4*)(Wp + (size_t)((ct * 16 + ks) * 64 + ln) * 8) = o4;
}

// ROUND 11: R2 structure + K-slab double-buffered pipeline + depth-1
// operand prefetch + paired sincos.
// R4 post-mortem: per-lane B loads from global = 32+ cache lines per
// wave-instr (rows 2KB apart) -> VMEM request amplification, MfmaUtil 9%.
// Reverted to LDS staging. R2's 43us was phase serialization: one-shot
// full-K stage behind a barrier + per-iter exposed aw(L2)/bs(LDS) latency.
// Fixes here:
//  - 4 K-slabs of 128, buf[2] (2x16KB bf16): next-slab global loads issued
//    BEFORE the slab's 80 MFMAs (latency hidden), ds_write after barrier.
//  - bs/aw ping-pong: operands for step k+1 load during step k's 20 MFMAs.
//  - cols interleaved re/im -> one fract/sin/cos per pair (trans ops halved).
//  - chunk XOR swizzle (slot = chunk ^ (row&7)): reads 2-way (free),
//    writes 4-way, vs 786k conflicts in R2.
// 8 waves/CU by design (ILP over TLP): launch_bounds(512,2) for reg room.
__global__ __launch_bounds__(512, 2) void fused_kernel(
    const float* __restrict__ inputs, const float* __restrict__ targets,
    const float* __restrict__ bias, const unsigned short* __restrict__ Wp,
    float* __restrict__ out)
{
    __shared__ __align__(16) unsigned short buf[2][64][16][8];  // 32 KiB
    __shared__ float R[8][64][3];                               // 6 KiB
    const int tid  = threadIdx.x;
    const int base = blockIdx.x * 64;
    const int wid  = tid >> 6;
    const int lane = tid & 63;
    const int quad = lane >> 4;
    const int lcol = lane & 15;
    const int ct0  = wid * 5;

    // staging map: thread owns row ss, fp32 cols [su*16, su*16+16) per slab
    const int ss = tid >> 3;
    const int su = tid & 7;
    const float4* sp = (const float4*)(inputs + (size_t)(base + ss) * DIMK + su * 16);
    const int slot0 = (2 * su)     ^ (ss & 7);
    const int slot1 = (2 * su + 1) ^ (ss & 7);

    float4 g0, g1, g2, g3;

#define WRITE_STAGE(nb) do {                                                  \
    union { __bf16 h[8]; uint4 u; } c0_, c1_;                                 \
    c0_.h[0]=(__bf16)g0.x; c0_.h[1]=(__bf16)g0.y;                             \
    c0_.h[2]=(__bf16)g0.z; c0_.h[3]=(__bf16)g0.w;                             \
    c0_.h[4]=(__bf16)g1.x; c0_.h[5]=(__bf16)g1.y;                             \
    c0_.h[6]=(__bf16)g1.z; c0_.h[7]=(__bf16)g1.w;                             \
    c1_.h[0]=(__bf16)g2.x; c1_.h[1]=(__bf16)g2.y;                             \
    c1_.h[2]=(__bf16)g2.z; c1_.h[3]=(__bf16)g2.w;                             \
    c1_.h[4]=(__bf16)g3.x; c1_.h[5]=(__bf16)g3.y;                             \
    c1_.h[6]=(__bf16)g3.z; c1_.h[7]=(__bf16)g3.w;                             \
    *(uint4*)&buf[nb][ss][slot0][0] = c0_.u;                                  \
    *(uint4*)&buf[nb][ss][slot1][0] = c1_.u;                                  \
} while (0)

#define LDBS(dst, bb, kss)                                                    \
    { _Pragma("unroll") for (int st_ = 0; st_ < 4; ++st_)                     \
        dst[st_] = *(const bf16x8*)&buf[bb][st_ * 16 + lcol]                  \
                       [((kss) * 4 + quad) ^ (lcol & 7)][0]; }

#define LDAW(dst, ksg)                                                        \
    { _Pragma("unroll") for (int t5_ = 0; t5_ < 5; ++t5_)                     \
        dst[t5_] = Wf[((size_t)(ct0 + t5_) * 16 + (ksg)) * 64 + lane]; }

#define DOMFMA(aww, bss)                                                      \
    { _Pragma("unroll") for (int t5_ = 0; t5_ < 5; ++t5_)                     \
        { _Pragma("unroll") for (int st_ = 0; st_ < 4; ++st_)                 \
            acc[t5_][st_] = __builtin_amdgcn_mfma_f32_16x16x32_bf16(          \
                aww[t5_], bss[st_], acc[t5_][st_], 0, 0, 0); } }

    // ---- prologue: stage slab 0 ----
    g0 = sp[0]; g1 = sp[1]; g2 = sp[2]; g3 = sp[3];
    WRITE_STAGE(0);
    __syncthreads();

    // per-lane target phases (pre-halved: sin(pi*z) = v_sin(z/2) revolutions)
    float xs[4], ys[4];
    #pragma unroll
    for (int st = 0; st < 4; ++st) {
        float2 t2 = *(const float2*)(targets + 2 * (base + st * 16 + lcol));
        xs[st] = 0.5f * t2.x;
        ys[st] = 0.5f * t2.y;
    }

    floatx4 acc[5][4];
    #pragma unroll
    for (int t5 = 0; t5 < 5; ++t5)
        #pragma unroll
        for (int st = 0; st < 4; ++st) acc[t5][st] = (floatx4){0.f, 0.f, 0.f, 0.f};

    const bf16x8* Wf = (const bf16x8*)Wp;

    bf16x8 bsP[4], awP[5], bsQ[4], awQ[5];
    LDBS(bsP, 0, 0);
    LDAW(awP, 0);

    #pragma unroll
    for (int kt = 0; kt < 4; ++kt) {
        const int cur = kt & 1;
        if (kt < 3) {   // issue next-slab global loads; land under the MFMAs
            g0 = sp[(kt + 1) * 32 + 0];
            g1 = sp[(kt + 1) * 32 + 1];
            g2 = sp[(kt + 1) * 32 + 2];
            g3 = sp[(kt + 1) * 32 + 3];
        }
        #pragma unroll
        for (int ks = 0; ks < 4; ++ks) {
            const int ksg = kt * 4 + ks;
            if (ksg & 1) {
                if (ks < 3)      { LDBS(bsP, cur, ks + 1); LDAW(awP, ksg + 1); }
                else if (kt < 3) { LDAW(awP, ksg + 1); }     // cross-slab aw
                DOMFMA(awQ, bsQ);
            } else {
                if (ks < 3)      { LDBS(bsQ, cur, ks + 1); LDAW(awQ, ksg + 1); }
                else if (kt < 3) { LDAW(awQ, ksg + 1); }
                DOMFMA(awP, bsP);
            }
        }
        __syncthreads();                 // all waves done reading buf[cur]
        if (kt < 3) {
            WRITE_STAGE(1 - cur);        // implicit vmcnt wait on g0..g3
            __syncthreads();             // buf[1-cur] ready
            // preload bs for next slab's ksg = (kt+1)*4 (even -> P set)
            LDBS(bsP, 1 - cur, 0);
        }
    }

    // ---- epilogue: paired re/im cols share one sincos ----
    float pd[4]  = {0.f, 0.f, 0.f, 0.f};
    float pr[4]  = {0.f, 0.f, 0.f, 0.f};
    float pim[4] = {0.f, 0.f, 0.f, 0.f};

    #pragma unroll
    for (int t5 = 0; t5 < 5; ++t5)
        #pragma unroll
        for (int p = 0; p < 2; ++p) {
            int colw = (ct0 + t5) * 16 + quad * 4 + 2 * p;   // even slot
            if (colw < NOUT) {
                int j = colw >> 1;
                int r = j / 17;
                int c = j - r * 17;
                float cf = (float)c, rf = (float)r;
                float be = bias[j];
                float bo = bias[j + NPARC];
                #pragma unroll
                for (int st = 0; st < 4; ++st) {
                    float ve = acc[t5][st][2 * p]     + be;
                    float vo = acc[t5][st][2 * p + 1] + bo;
                    float u = fmaf(cf, xs[st], rf * ys[st]);
                    u = __builtin_amdgcn_fractf(u);
                    float sn = __builtin_amdgcn_sinf(u);
                    float cs = __builtin_amdgcn_cosf(u);
                    pd[st]  = fmaf(ve, ve, pd[st]);
                    pd[st]  = fmaf(vo, vo, pd[st]);
                    pr[st]  = fmaf(ve, cs, pr[st]);
                    pr[st]  = fmaf(-vo, sn, pr[st]);
                    pim[st] = fmaf(ve, sn, pim[st]);
                    pim[st] = fmaf(vo, cs, pim[st]);
                }
            }
        }

    // reduce across the 4 quads — butterfly on lane bits 4,5
    #pragma unroll
    for (int d = 16; d < 64; d <<= 1)
        #pragma unroll
        for (int st = 0; st < 4; ++st) {
            pd[st]  += __shfl_xor(pd[st], d, 64);
            pr[st]  += __shfl_xor(pr[st], d, 64);
            pim[st] += __shfl_xor(pim[st], d, 64);
        }

    if (lane < 16) {
        #pragma unroll
        for (int st = 0; st < 4; ++st) {
            int sl = st * 16 + lane;
            R[wid][sl][0] = pd[st];
            R[wid][sl][1] = pr[st];
            R[wid][sl][2] = pim[st];
        }
    }
    __syncthreads();

    if (tid < 64) {
        float sd = 0.f, sr = 0.f, si = 0.f;
        #pragma unroll
        for (int w = 0; w < 8; ++w) {
            sd += R[w][tid][0];
            sr += R[w][tid][1];
            si += R[w][tid][2];
        }
        out[base + tid] = (sr * sr + si * si) / (4.0f * sd);
    }
#undef WRITE_STAGE
#undef LDBS
#undef LDAW
#undef DOMFMA
}

extern "C" void kernel_launch(void* const* d_in, const int* in_sizes, int n_in,
                              void* d_out, int out_size, void* d_ws, size_t ws_size,
                              hipStream_t stream) {
    const float* inputs  = (const float*)d_in[0];
    const float* targets = (const float*)d_in[1];
    const float* W       = (const float*)d_in[2];
    const float* bias    = (const float*)d_in[3];
    unsigned short* Wp   = (unsigned short*)d_ws;   // 640 KiB of ws

    prep_w<<<160, 256, 0, stream>>>(W, Wp);
    fused_kernel<<<BATCH / 64, 512, 0, stream>>>(inputs, targets, bias, Wp, (float*)d_out);
}

// Round 7
// 120.302 us; speedup vs baseline: 1.3181x; 1.0077x over previous
//
#include <hip/hip_runtime.h>

#define NPARC 289
#define NOUT  578
#define DIMK  512
#define BATCH 32768

typedef __bf16 bf16x8 __attribute__((ext_vector_type(8)));
typedef float floatx4 __attribute__((ext_vector_type(4)));

__device__ __forceinline__ unsigned short f2bf(float f) {
    unsigned u = __float_as_uint(f);
    u = (u + 0x7fffu + ((u >> 16) & 1u)) >> 16;
    return (unsigned short)u;
}

// prep (verified in R5): INTERLEAVED col slots — slot 2j = re col j, slot
// 2j+1 = im col j (orig row j+289) so the epilogue shares one sincos per
// (re,im) pair. 16x16x32 A-operand fragment order:
// m = ct*16 + (lane&15), k = ks*32 + (lane>>4)*8 + j. Slots >= 578 zero.
__global__ void prep_w(const float* __restrict__ W, unsigned short* __restrict__ Wp) {
    int wid = threadIdx.x >> 6;
    int lane = threadIdx.x & 63;
    int slot = blockIdx.x * 4 + wid;         // [0, 640)
    int k = lane * 8;
    unsigned short v[8];
    if (slot < NOUT) {
        int o = (slot & 1) ? NPARC + (slot >> 1) : (slot >> 1);
        const float* src = W + (size_t)o * DIMK + k;
        #pragma unroll
        for (int j = 0; j < 8; ++j) v[j] = f2bf(src[j]);
    } else {
        #pragma unroll
        for (int j = 0; j < 8; ++j) v[j] = 0;
    }
    int ct = slot >> 4;
    int ks = k >> 5;
    int ln = (((k >> 3) & 3) << 4) + (slot & 15);
    uint4 o4;
    o4.x = (unsigned)v[0] | ((unsigned)v[1] << 16);
    o4.y = (unsigned)v[2] | ((unsigned)v[3] << 16);
    o4.z = (unsigned)v[4] | ((unsigned)v[5] << 16);
    o4.w = (unsigned)v[6] | ((unsigned)v[7] << 16);
    *(uint4*)(Wp + (size_t)((ct * 16 + ks) * 64 + ln) * 8) = o4;
}

// ROUND 13: async global_load_lds K-slab pipeline.
// R6 post-mortem: acc regs/thread = 64*640/512 = 80 is forced — any geometry
// with smaller acc loses output coverage (R6's absmax=1.6 bug). With 80 AGPR
// + operands, 512-thread blocks sit at 1 block/CU = 2 waves/SIMD; TLP is
// capped by algebra. R5 proved reg-prefetch gets collapsed by the compiler
// (VGPR_Count=88). The uncollapsible mechanism: global_load_lds (async DMA,
// no reg destination). K in 4 slabs of 128 fp32; buf[2] 32KB each; next
// slab's loads issue BEFORE the current slab's 80 MFMAs/wave, one barrier
// per slab whose vmcnt-drain waits on loads issued ~4 ksg earlier (cheap).
// gload_lds writes linearly -> bank swizzle via PRE-PERMUTED SOURCE (rule
// 21): LDS phys 16B-chunk c of row r holds logical chunk c^(r&15); reads
// XOR identically -> ds_read_b128 2-way (free) instead of 16-way.
// bs: depth-1 raw-fp32 prefetch (rA/rB) + cvt_pk at use. aw: depth-1
// double-set (aw0/aw1). sched_barrier(0) brackets each 20-MFMA cluster,
// setprio(1) inside (T5). ~140 VGPR + 80 AGPR < 256: no spill at (512,2).
__global__ __launch_bounds__(512, 2) void fused_kernel(
    const float* __restrict__ inputs, const float* __restrict__ targets,
    const float* __restrict__ bias, const unsigned short* __restrict__ Wp,
    float* __restrict__ out)
{
    __shared__ __align__(16) float buf[2][64 * 128];   // 2 x 32 KiB fp32 slabs
    __shared__ float R[8][64][3];                      // 6 KiB
    const int tid  = threadIdx.x;
    const int base = blockIdx.x * 64;
    const int wid  = tid >> 6;
    const int lane = tid & 63;
    const int quad = lane >> 4;
    const int lcol = lane & 15;
    const int ct0  = wid * 5;
    const bf16x8* Wf = (const bf16x8*)Wp;

    // stage: wave w issues 4 x 1KB global_load_lds per slab. Instr I=w*4+j
    // covers LDS bytes [I*1024, I*1024+1024) = rows r=I*2+(lane>>5), phys
    // chunk lane&31; lane fetches logical chunk (lane&31)^(r&15) of row r.
#define STAGE(nb, kt) do {                                                    \
    _Pragma("unroll") for (int j_ = 0; j_ < 4; ++j_) {                        \
        int I_ = wid * 4 + j_;                                                \
        int r_ = I_ * 2 + (lane >> 5);                                        \
        int cl_ = (lane & 31) ^ (r_ & 15);                                    \
        const float* g_ = inputs + (size_t)(base + r_) * DIMK + (kt) * 128 + cl_ * 4; \
        void* l_ = (char*)&buf[nb][0] + I_ * 1024;                            \
        __builtin_amdgcn_global_load_lds(                                     \
            (const __attribute__((address_space(1))) unsigned int*)g_,        \
            (__attribute__((address_space(3))) unsigned int*)l_, 16, 0, 0);   \
    }                                                                         \
} while (0)

    // raw fp32 fragment read (8 floats = 2 swizzled b128) for slab-local ksg
#define LDRAW(R_, nb, kl) do {                                                \
    _Pragma("unroll") for (int st_ = 0; st_ < 4; ++st_) {                     \
        int s_ = st_ * 16 + lcol;                                             \
        int cb_ = (kl) * 8 + quad * 2;                                        \
        const char* p_ = (const char*)&buf[nb][0] + s_ * 512;                 \
        R_[2 * st_]     = *(const floatx4*)(p_ + ((cb_)     ^ (s_ & 15)) * 16); \
        R_[2 * st_ + 1] = *(const floatx4*)(p_ + ((cb_ + 1) ^ (s_ & 15)) * 16); \
    }                                                                         \
} while (0)

#define LDAW(dst, ksg)                                                        \
    { _Pragma("unroll") for (int t5_ = 0; t5_ < 5; ++t5_)                     \
        dst[t5_] = Wf[((size_t)(ct0 + t5_) * 16 + (ksg)) * 64 + lane]; }

    // one K-step: prefetch next raw + next aw, cvt current raw, 20 MFMA
#define KS(nb, ksg, RU, RP, PF, AWU, AWP) do {                                \
    if (PF) LDRAW(RP, nb, ((ksg) & 3) + 1);                                   \
    if ((ksg) < 15) LDAW(AWP, (ksg) + 1);                                     \
    bf16x8 bsv[4];                                                            \
    _Pragma("unroll") for (int st_ = 0; st_ < 4; ++st_) {                     \
        union { __bf16 h[8]; bf16x8 v; } cu_;                                 \
        cu_.h[0] = (__bf16)RU[2 * st_][0];     cu_.h[1] = (__bf16)RU[2 * st_][1]; \
        cu_.h[2] = (__bf16)RU[2 * st_][2];     cu_.h[3] = (__bf16)RU[2 * st_][3]; \
        cu_.h[4] = (__bf16)RU[2 * st_ + 1][0]; cu_.h[5] = (__bf16)RU[2 * st_ + 1][1]; \
        cu_.h[6] = (__bf16)RU[2 * st_ + 1][2]; cu_.h[7] = (__bf16)RU[2 * st_ + 1][3]; \
        bsv[st_] = cu_.v;                                                     \
    }                                                                         \
    __builtin_amdgcn_sched_barrier(0);                                        \
    __builtin_amdgcn_s_setprio(1);                                            \
    _Pragma("unroll") for (int t5_ = 0; t5_ < 5; ++t5_)                       \
        { _Pragma("unroll") for (int st_ = 0; st_ < 4; ++st_)                 \
            acc[t5_][st_] = __builtin_amdgcn_mfma_f32_16x16x32_bf16(          \
                AWU[t5_], bsv[st_], acc[t5_][st_], 0, 0, 0); }                \
    __builtin_amdgcn_s_setprio(0);                                            \
    __builtin_amdgcn_sched_barrier(0);                                        \
} while (0)

    floatx4 acc[5][4];
    #pragma unroll
    for (int t5 = 0; t5 < 5; ++t5)
        #pragma unroll
        for (int st = 0; st < 4; ++st) acc[t5][st] = (floatx4){0.f, 0.f, 0.f, 0.f};

    bf16x8 aw0[5], aw1[5];
    floatx4 rA[8], rB[8];

    // prologue: stage slab 0, preload aw(0)
    STAGE(0, 0);
    LDAW(aw0, 0);
    __syncthreads();                      // vmcnt drain: slab 0 resident

    // slab 0 (buf 0)
    STAGE(1, 1);
    LDRAW(rA, 0, 0);
    KS(0, 0,  rA, rB, 1, aw0, aw1);
    KS(0, 1,  rB, rA, 1, aw1, aw0);
    KS(0, 2,  rA, rB, 1, aw0, aw1);
    KS(0, 3,  rB, rA, 0, aw1, aw0);
    __syncthreads();                      // slab 1 resident

    // slab 1 (buf 1)
    STAGE(0, 2);
    LDRAW(rA, 1, 0);
    KS(1, 4,  rA, rB, 1, aw0, aw1);
    KS(1, 5,  rB, rA, 1, aw1, aw0);
    KS(1, 6,  rA, rB, 1, aw0, aw1);
    KS(1, 7,  rB, rA, 0, aw1, aw0);
    __syncthreads();                      // slab 2 resident

    // slab 2 (buf 0)
    STAGE(1, 3);
    LDRAW(rA, 0, 0);
    KS(0, 8,  rA, rB, 1, aw0, aw1);
    KS(0, 9,  rB, rA, 1, aw1, aw0);
    KS(0, 10, rA, rB, 1, aw0, aw1);
    KS(0, 11, rB, rA, 0, aw1, aw0);
    __syncthreads();                      // slab 3 resident

    // slab 3 (buf 1)
    LDRAW(rA, 1, 0);
    KS(1, 12, rA, rB, 1, aw0, aw1);
    KS(1, 13, rB, rA, 1, aw1, aw0);
    KS(1, 14, rA, rB, 1, aw0, aw1);
    KS(1, 15, rB, rA, 0, aw1, aw0);

    // ---- epilogue: paired re/im cols share one sincos (revolutions) ----
    float xs[4], ys[4];
    #pragma unroll
    for (int st = 0; st < 4; ++st) {
        float2 t2 = *(const float2*)(targets + 2 * (base + st * 16 + lcol));
        xs[st] = 0.5f * t2.x;             // sin(pi*z) = v_sin(z/2 rev)
        ys[st] = 0.5f * t2.y;
    }

    float pd[4]  = {0.f, 0.f, 0.f, 0.f};
    float pr[4]  = {0.f, 0.f, 0.f, 0.f};
    float pim[4] = {0.f, 0.f, 0.f, 0.f};

    #pragma unroll
    for (int t5 = 0; t5 < 5; ++t5)
        #pragma unroll
        for (int p = 0; p < 2; ++p) {
            int colw = (ct0 + t5) * 16 + quad * 4 + 2 * p;   // even slot
            if (colw < NOUT) {
                int jj = colw >> 1;
                int r = jj / 17;
                int c = jj - r * 17;
                float cf = (float)c, rf = (float)r;
                float be = bias[jj];
                float bo = bias[jj + NPARC];
                #pragma unroll
                for (int st = 0; st < 4; ++st) {
                    float ve = acc[t5][st][2 * p]     + be;
                    float vo = acc[t5][st][2 * p + 1] + bo;
                    float u = fmaf(cf, xs[st], rf * ys[st]);
                    u = __builtin_amdgcn_fractf(u);
                    float sn = __builtin_amdgcn_sinf(u);
                    float cs = __builtin_amdgcn_cosf(u);
                    pd[st]  = fmaf(ve, ve, pd[st]);
                    pd[st]  = fmaf(vo, vo, pd[st]);
                    pr[st]  = fmaf(ve, cs, pr[st]);
                    pr[st]  = fmaf(-vo, sn, pr[st]);
                    pim[st] = fmaf(ve, sn, pim[st]);
                    pim[st] = fmaf(vo, cs, pim[st]);
                }
            }
        }

    // fold the 4 quads (weight-col rows) — butterfly on lane bits 4,5
    #pragma unroll
    for (int d = 16; d < 64; d <<= 1)
        #pragma unroll
        for (int st = 0; st < 4; ++st) {
            pd[st]  += __shfl_xor(pd[st], d, 64);
            pr[st]  += __shfl_xor(pr[st], d, 64);
            pim[st] += __shfl_xor(pim[st], d, 64);
        }

    if (lane < 16) {
        #pragma unroll
        for (int st = 0; st < 4; ++st) {
            int sl = st * 16 + lane;
            R[wid][sl][0] = pd[st];
            R[wid][sl][1] = pr[st];
            R[wid][sl][2] = pim[st];
        }
    }
    __syncthreads();

    if (tid < 64) {
        float sd = 0.f, sr = 0.f, si = 0.f;
        #pragma unroll
        for (int w = 0; w < 8; ++w) {
            sd += R[w][tid][0];
            sr += R[w][tid][1];
            si += R[w][tid][2];
        }
        out[base + tid] = (sr * sr + si * si) / (4.0f * sd);
    }
#undef STAGE
#undef LDRAW
#undef LDAW
#undef KS
}

extern "C" void kernel_launch(void* const* d_in, const int* in_sizes, int n_in,
                              void* d_out, int out_size, void* d_ws, size_t ws_size,
                              hipStream_t stream) {
    const float* inputs  = (const float*)d_in[0];
    const float* targets = (const float*)d_in[1];
    const float* W       = (const float*)d_in[2];
    const float* bias    = (const float*)d_in[3];
    unsigned short* Wp   = (unsigned short*)d_ws;   // 640 KiB of ws

    prep_w<<<160, 256, 0, stream>>>(W, Wp);
    fused_kernel<<<BATCH / 64, 512, 0, stream>>>(inputs, targets, bias, Wp, (float*)d_out);
}